// Round 4
// baseline (7860.669 us; speedup 1.0000x reference)
//
#include <hip/hip_runtime.h>
#include <hip/hip_bf16.h>
#include <stdint.h>

#define B_ 64
#define S_ 512
#define I_ 512
#define H_ 1024

typedef __attribute__((ext_vector_type(8))) __bf16 bf16x8;
typedef __attribute__((ext_vector_type(4))) float f32x4;

__device__ __forceinline__ unsigned short f2bf(float f) {
    unsigned u = __float_as_uint(f);
    u += 0x7FFFu + ((u >> 16) & 1u);   // RNE
    return (unsigned short)(u >> 16);
}

__device__ __forceinline__ bf16x8 ld8(const unsigned short* p) {
    return *(const bf16x8*)p;
}

// ---------- prep: convert x and W_ih to bf16 ----------
__global__ __launch_bounds__(256) void gru_prep(const float* __restrict__ x,
                                                const float* __restrict__ wih,
                                                unsigned short* __restrict__ xbf,
                                                unsigned short* __restrict__ wbf) {
    const int NX = (B_ * S_ * I_) / 4;   // 4194304 float4
    const int NW = (3 * H_ * I_) / 4;    // 393216 float4
    int stride = gridDim.x * blockDim.x;
    for (int i = blockIdx.x * blockDim.x + threadIdx.x; i < NX + NW; i += stride) {
        float4 v = (i < NX) ? ((const float4*)x)[i] : ((const float4*)wih)[i - NX];
        ushort4 o;
        o.x = f2bf(v.x); o.y = f2bf(v.y); o.z = f2bf(v.z); o.w = f2bf(v.w);
        if (i < NX) ((ushort4*)xbf)[i] = o; else ((ushort4*)wbf)[i - NX] = o;
    }
}

// ---------- persistent scan ----------
// 128 blocks, block g owns h columns [8g, 8g+8). 4 waves, wave w = batches [16w,16w+16).
//
// Sync fabric (round 4): ZERO cache-maintenance ops. All cross-block data
// (hbuf, cnt) moves via relaxed agent-scope atomics, which bypass L1/L2 to the
// mall. Producer: h stores as agent atomics; __syncthreads' implicit
// s_waitcnt vmcnt(0) guarantees they are acked at the mall; tid0 then bumps
// cnt[t+1] (mall atomic RMW). Consumer: tid0 polls cnt[t] (mall atomic load),
// __syncthreads, then h loads as agent atomics (mall-direct, provably fresh).
// x / W_ih / mask / out stay normally cached and now remain L1/L2-resident
// across steps (nothing invalidates them).
//
// h-phase latency hiding: all 64 8B agent loads are pre-issued into a register
// array (~128 VGPRs; 1 block/CU so up to 512 VGPRs/wave available), then
// drained into MFMAs — one mall round-trip of latency, not 32.
__global__ __launch_bounds__(256, 1) void gru_scan(
    const unsigned short* __restrict__ xbf,
    const unsigned short* __restrict__ wihbf,
    const float* __restrict__ mask,
    const float* __restrict__ init_h,
    const float* __restrict__ dmask,
    const float* __restrict__ Whh,
    const float* __restrict__ bih,
    const float* __restrict__ bhh,
    float* __restrict__ out,
    float* __restrict__ out_last,
    unsigned* __restrict__ cnt,          // [S_+1] step counters, zeroed at launch
    unsigned short* __restrict__ hbuf)   // 2 buffers of 64*1024 bf16
{
    // rows 0-7: W_hh r-rows, 8-15: z-rows, 16-23: n-rows. stride 1032 (pad 8).
    __shared__ unsigned short wlds[24 * 1032];

    const int g   = blockIdx.x;
    const int tid = threadIdx.x;
    const int w   = tid >> 6;        // wave = M-tile (batches)
    const int l   = tid & 63;
    const int q   = l >> 4;          // k-quad
    const int c   = l & 15;          // n-col (weight row) / m-row for A
    const int c8  = c & 7;

    // stage W_hh slice -> LDS bf16
    for (int idx = tid; idx < 24 * 1024; idx += 256) {
        int row = idx >> 10, col = idx & 1023;
        int sr = (row < 8) ? (g * 8 + row)
               : (row < 16) ? (H_ + g * 8 + row - 8)
                            : (2 * H_ + g * 8 + row - 16);
        wlds[row * 1032 + col] = f2bf(Whh[(size_t)sr * H_ + col]);
    }

    const int jd = g * 8 + c8;
    const int wr_rz = (c < 8) ? (g * 8 + c) : (H_ + g * 8 + (c - 8));
    const int wr_xn = 2 * H_ + jd;
    const float brz_b = (c < 8) ? (bih[g * 8 + c] + bhh[g * 8 + c])
                                : (bih[H_ + g * 8 + c - 8] + bhh[H_ + g * 8 + c - 8]);
    const float bxn_b = bih[2 * H_ + jd];
    const float bhn_b = bhh[2 * H_ + jd];

    const int batch_A = w * 16 + c;  // A-frag batch (m = lane&15)

    // per-(reg) state, C-layout batches
    float dm[4], hd[4], mc[4];
    int batch_C[4];
    #pragma unroll
    for (int r = 0; r < 4; ++r) {
        batch_C[r] = w * 16 + q * 4 + r;
        dm[r] = dmask[batch_C[r] * H_ + jd];
        float m1 = mask[batch_C[r] * S_ + 0];
        float h0 = init_h[batch_C[r] * H_ + jd];
        hd[r] = h0 * (dm[r] * m1 + 1.0f - m1);   // pre-dropped h for step 1
        mc[r] = m1;
        if (c < 8)
            __hip_atomic_store(&hbuf[65536 + batch_C[r] * H_ + jd], f2bf(hd[r]),
                               __ATOMIC_RELAXED, __HIP_MEMORY_SCOPE_AGENT);
    }
    __syncthreads();   // LDS staged + all agent h-stores acked at the mall
    if (tid == 0)
        __hip_atomic_fetch_add(&cnt[1], 1u, __ATOMIC_RELAXED, __HIP_MEMORY_SCOPE_AGENT);

    const int off_rz = c * 1032 + q * 8;
    const int off_hn = (16 + c8) * 1032 + q * 8;

    for (int t = 1; t <= S_; ++t) {
        const int s = t - 1;
        f32x4 arz, axn, ahn;
        #pragma unroll
        for (int r = 0; r < 4; ++r) { arz[r] = brz_b; axn[r] = bxn_b; ahn[r] = bhn_b; }

        float mn[4];
        if (t < S_) {
            #pragma unroll
            for (int r = 0; r < 4; ++r) mn[r] = mask[batch_C[r] * S_ + t];
        }

        // ---- x phase (h-independent: overlaps other blocks finishing step t-1;
        //      all loads normally cached, W_ih stays L1-resident) ----
        {
            const unsigned short* xp  = xbf + (size_t)batch_A * (S_ * I_) + s * I_ + q * 8;
            const unsigned short* wrz = wihbf + (size_t)wr_rz * I_ + q * 8;
            const unsigned short* wxn = wihbf + (size_t)wr_xn * I_ + q * 8;
            #pragma unroll 4
            for (int ki = 0; ki < 16; ++ki) {
                bf16x8 a  = ld8(xp  + ki * 32);
                bf16x8 b0 = ld8(wrz + ki * 32);
                bf16x8 b1 = ld8(wxn + ki * 32);
                arz = __builtin_amdgcn_mfma_f32_16x16x32_bf16(a, b0, arz, 0, 0, 0);
                axn = __builtin_amdgcn_mfma_f32_16x16x32_bf16(a, b1, axn, 0, 0, 0);
            }
        }

        // ---- wait until every block posted h for step t ----
        if (tid == 0) {
            int spins = 0;
            while (__hip_atomic_load(&cnt[t], __ATOMIC_RELAXED,
                                     __HIP_MEMORY_SCOPE_AGENT) < 128u) {
                __builtin_amdgcn_s_sleep(1);
                if (++spins > 200000) break;   // safety valve: fail loud, don't hang
            }
        }
        __syncthreads();

        // ---- h phase: pre-issue ALL agent loads (one mall round-trip), then MFMA ----
        {
            const unsigned short* hp = hbuf + (t & 1) * 65536 + batch_A * H_ + q * 8;
            unsigned long long hu0[32], hu1[32];
            #pragma unroll
            for (int ki = 0; ki < 32; ++ki) {
                const unsigned long long* p = (const unsigned long long*)(hp + ki * 32);
                hu0[ki] = __hip_atomic_load(p,     __ATOMIC_RELAXED, __HIP_MEMORY_SCOPE_AGENT);
                hu1[ki] = __hip_atomic_load(p + 1, __ATOMIC_RELAXED, __HIP_MEMORY_SCOPE_AGENT);
            }
            #pragma unroll
            for (int ki = 0; ki < 32; ++ki) {
                union { unsigned long long u[2]; bf16x8 v; } cv;
                cv.u[0] = hu0[ki]; cv.u[1] = hu1[ki];
                bf16x8 b0 = *(const bf16x8*)&wlds[off_rz + ki * 32];
                bf16x8 b1 = *(const bf16x8*)&wlds[off_hn + ki * 32];
                arz = __builtin_amdgcn_mfma_f32_16x16x32_bf16(cv.v, b0, arz, 0, 0, 0);
                ahn = __builtin_amdgcn_mfma_f32_16x16x32_bf16(cv.v, b1, ahn, 0, 0, 0);
            }
        }

        // ---- gates + state update ----
        #pragma unroll
        for (int r = 0; r < 4; ++r) {
            float zpre = __shfl(arz[r], (l & 48) | ((c + 8) & 15), 64); // z lives 8 cols over
            float rr = __builtin_amdgcn_rcpf(1.0f + __expf(-arz[r]));
            float zz = __builtin_amdgcn_rcpf(1.0f + __expf(-zpre));
            float narg = axn[r] + rr * ahn[r];
            float E = __expf(-2.0f * fabsf(narg));
            float nn = copysignf((1.0f - E) * __builtin_amdgcn_rcpf(1.0f + E), narg);
            float m = mc[r];
            float curr = (1.0f - zz) * nn + zz * hd[r];
            float hnew = m * curr + (1.0f - m) * hd[r];
            if (t < S_) {
                hd[r] = hnew * (dm[r] * mn[r] + 1.0f - mn[r]);  // pre-drop for step t+1
                mc[r] = mn[r];
                if (c < 8)
                    __hip_atomic_store(&hbuf[((t + 1) & 1) * 65536 + batch_C[r] * H_ + jd],
                                       f2bf(hd[r]), __ATOMIC_RELAXED, __HIP_MEMORY_SCOPE_AGENT);
            } else if (c < 8) {
                out_last[batch_C[r] * H_ + jd] = hnew;
            }
            if (c < 8)
                out[((size_t)batch_C[r] * S_ + s) * H_ + jd] = hnew;   // plain cached store
        }

        if (t < S_) {
            __syncthreads();   // implicit vmcnt(0): agent h-stores acked at mall
            if (tid == 0)
                __hip_atomic_fetch_add(&cnt[t + 1], 1u, __ATOMIC_RELAXED,
                                       __HIP_MEMORY_SCOPE_AGENT);
        }
    }
}

extern "C" void kernel_launch(void* const* d_in, const int* in_sizes, int n_in,
                              void* d_out, int out_size, void* d_ws, size_t ws_size,
                              hipStream_t stream) {
    (void)in_sizes; (void)n_in; (void)out_size; (void)ws_size;
    const float* x     = (const float*)d_in[0];
    const float* mask  = (const float*)d_in[1];
    const float* inith = (const float*)d_in[2];
    const float* dmask = (const float*)d_in[3];
    const float* Wih   = (const float*)d_in[4];
    const float* Whh   = (const float*)d_in[5];
    const float* bih   = (const float*)d_in[6];
    const float* bhh   = (const float*)d_in[7];
    float* out      = (float*)d_out;
    float* out_last = out + (size_t)B_ * S_ * H_;

    char* ws = (char*)d_ws;
    unsigned* cnt         = (unsigned*)ws;                         // 8 KB (step counters)
    unsigned short* hbuf  = (unsigned short*)(ws + 8192);          // 256 KB (2x h_bf)
    unsigned short* xbf   = (unsigned short*)(ws + 8192 + 262144); // 32 MB
    unsigned short* wbf   = xbf + (size_t)B_ * S_ * I_;            // 3 MB

    hipMemsetAsync(ws, 0, 8192, stream);
    gru_prep<<<2048, 256, 0, stream>>>(x, Wih, xbf, wbf);
    gru_scan<<<128, 256, 0, stream>>>(xbf, wbf, mask, inith, dmask, Whh, bih, bhh,
                                      out, out_last, cnt, hbuf);
}

// Round 5
// 6344.251 us; speedup vs baseline: 1.2390x; 1.2390x over previous
//
#include <hip/hip_runtime.h>
#include <hip/hip_bf16.h>
#include <stdint.h>

#define B_ 64
#define S_ 512
#define I_ 512
#define H_ 1024
#define NB 64          // blocks; block g owns 16 h-columns [16g, 16g+16)

typedef __attribute__((ext_vector_type(8))) __bf16 bf16x8;
typedef __attribute__((ext_vector_type(4))) float f32x4;

__device__ __forceinline__ unsigned short f2bf(float f) {
    unsigned u = __float_as_uint(f);
    u += 0x7FFFu + ((u >> 16) & 1u);   // RNE
    return (unsigned short)(u >> 16);
}

__device__ __forceinline__ bf16x8 ld8(const unsigned short* p) {
    return *(const bf16x8*)p;
}

// ---------- prep: convert x to bf16 (weights are converted during LDS staging) ----------
__global__ __launch_bounds__(256) void gru_prep(const float* __restrict__ x,
                                                unsigned short* __restrict__ xbf) {
    const int NX = (B_ * S_ * I_) / 4;   // float4 count
    int stride = gridDim.x * blockDim.x;
    for (int i = blockIdx.x * blockDim.x + threadIdx.x; i < NX; i += stride) {
        float4 v = ((const float4*)x)[i];
        ushort4 o;
        o.x = f2bf(v.x); o.y = f2bf(v.y); o.z = f2bf(v.z); o.w = f2bf(v.w);
        ((ushort4*)xbf)[i] = o;
    }
}

// ---------- persistent scan ----------
// 64 blocks, block g owns h columns [16g,16g+16). 4 waves, wave w = batches [16w,16w+16).
//
// Sync fabric (round 5): store-only flags, one per block, each on its OWN 128B
// line (stride 32 dwords) -> no atomic RMWs, no shared hot line. Producer:
// __syncthreads (implicit vmcnt(0): agent h-stores acked at mall) then tid0
// does ONE relaxed agent store flag[g]=t+1. Consumer: wave 0, lane i polls
// flag[i] -> all 64 flags in a single load per iteration, __all() combines.
// h exchange: relaxed agent atomics (mall-direct, proven R1/R4); h-phase
// pre-issues all 64 8B loads then drains into MFMAs.
__global__ __launch_bounds__(256, 1) void gru_scan(
    const unsigned short* __restrict__ xbf,
    const float* __restrict__ Wih,
    const float* __restrict__ mask,
    const float* __restrict__ init_h,
    const float* __restrict__ dmask,
    const float* __restrict__ Whh,
    const float* __restrict__ bih,
    const float* __restrict__ bhh,
    float* __restrict__ out,
    float* __restrict__ out_last,
    unsigned* __restrict__ flags,        // NB flags at stride 32 dwords, zeroed at launch
    unsigned short* __restrict__ hbuf)   // 2 buffers of 64*1024 bf16
{
    // W_hh rows for this block: 0-15 = r, 16-31 = z, 32-47 = n. stride 1032 shorts
    // (2064 B: 16B-aligned rows, 2-way-only bank aliasing = free).
    __shared__ unsigned short wlds[48 * 1032];
    // W_ih rows, same row order. stride 520 shorts (1040 B, 16B-aligned).
    __shared__ unsigned short wxlds[48 * 520];

    const int g   = blockIdx.x;
    const int tid = threadIdx.x;
    const int w   = tid >> 6;        // wave = M-tile (batches)
    const int l   = tid & 63;
    const int q   = l >> 4;          // k-quad
    const int c   = l & 15;          // n-col within block / m-row for A

    // stage W_hh slice -> LDS bf16 (48 rows x 1024)
    for (int idx = tid; idx < 48 * 1024; idx += 256) {
        int row = idx >> 10, col = idx & 1023;
        int sr = (row < 16) ? (g * 16 + row)
               : (row < 32) ? (H_ + g * 16 + row - 16)
                            : (2 * H_ + g * 16 + row - 32);
        wlds[row * 1032 + col] = f2bf(Whh[(size_t)sr * H_ + col]);
    }
    // stage W_ih slice -> LDS bf16 (48 rows x 512)
    for (int idx = tid; idx < 48 * 512; idx += 256) {
        int row = idx >> 9, col = idx & 511;
        int sr = (row < 16) ? (g * 16 + row)
               : (row < 32) ? (H_ + g * 16 + row - 16)
                            : (2 * H_ + g * 16 + row - 32);
        wxlds[row * 520 + col] = f2bf(Wih[(size_t)sr * I_ + col]);
    }

    const int jd = g * 16 + c;               // this lane's output column
    const float b_r  = bih[jd] + bhh[jd];
    const float b_z  = bih[H_ + jd] + bhh[H_ + jd];
    const float bxn_b = bih[2 * H_ + jd];
    const float bhn_b = bhh[2 * H_ + jd];

    const int batch_A = w * 16 + c;          // A-frag batch (m = lane&15)

    // per-reg state, C-layout batches
    float dm[4], hd[4], mc[4];
    int batch_C[4];
    #pragma unroll
    for (int r = 0; r < 4; ++r) {
        batch_C[r] = w * 16 + q * 4 + r;
        dm[r] = dmask[batch_C[r] * H_ + jd];
        float m1 = mask[batch_C[r] * S_ + 0];
        float h0 = init_h[batch_C[r] * H_ + jd];
        hd[r] = h0 * (dm[r] * m1 + 1.0f - m1);   // pre-dropped h for step 1
        mc[r] = m1;
        __hip_atomic_store(&hbuf[65536 + batch_C[r] * H_ + jd], f2bf(hd[r]),
                           __ATOMIC_RELAXED, __HIP_MEMORY_SCOPE_AGENT);
    }
    __syncthreads();   // LDS staged + agent h-stores acked at the mall
    if (tid == 0)
        __hip_atomic_store(&flags[g * 32], 1u, __ATOMIC_RELAXED, __HIP_MEMORY_SCOPE_AGENT);

    const int offx_r = c * 520,  offx_z = (16 + c) * 520,  offx_n = (32 + c) * 520;
    const int offh_r = c * 1032, offh_z = (16 + c) * 1032, offh_n = (32 + c) * 1032;

    for (int t = 1; t <= S_; ++t) {
        const int s = t - 1;
        f32x4 ar, az, axn, ahn;
        #pragma unroll
        for (int r = 0; r < 4; ++r) { ar[r] = b_r; az[r] = b_z; axn[r] = bxn_b; ahn[r] = bhn_b; }

        float mn[4];
        if (t < S_) {
            #pragma unroll
            for (int r = 0; r < 4; ++r) mn[r] = mask[batch_C[r] * S_ + t];
        }

        // ---- x phase (h-independent; A cached from global, B from LDS) ----
        {
            const unsigned short* xp = xbf + (size_t)batch_A * (S_ * I_) + s * I_ + q * 8;
            #pragma unroll 4
            for (int ki = 0; ki < 16; ++ki) {
                bf16x8 a  = ld8(xp + ki * 32);
                bf16x8 br = *(const bf16x8*)&wxlds[offx_r + q * 8 + ki * 32];
                bf16x8 bz = *(const bf16x8*)&wxlds[offx_z + q * 8 + ki * 32];
                bf16x8 bn = *(const bf16x8*)&wxlds[offx_n + q * 8 + ki * 32];
                ar  = __builtin_amdgcn_mfma_f32_16x16x32_bf16(a, br, ar, 0, 0, 0);
                az  = __builtin_amdgcn_mfma_f32_16x16x32_bf16(a, bz, az, 0, 0, 0);
                axn = __builtin_amdgcn_mfma_f32_16x16x32_bf16(a, bn, axn, 0, 0, 0);
            }
        }

        // ---- wait until every block posted h for step t (wave 0, one load/iter) ----
        if (tid < 64) {
            int spins = 0;
            for (;;) {
                unsigned v = __hip_atomic_load(&flags[l * 32], __ATOMIC_RELAXED,
                                               __HIP_MEMORY_SCOPE_AGENT);
                if (__all(v >= (unsigned)t)) break;
                __builtin_amdgcn_s_sleep(1);
                if (++spins > 150000) break;   // safety valve: fail loud, don't hang
            }
        }
        __syncthreads();

        // ---- h phase: pre-issue ALL agent loads (one mall round-trip), then MFMA ----
        {
            const unsigned short* hp = hbuf + (t & 1) * 65536 + batch_A * H_ + q * 8;
            unsigned long long hu0[32], hu1[32];
            #pragma unroll
            for (int ki = 0; ki < 32; ++ki) {
                const unsigned long long* p = (const unsigned long long*)(hp + ki * 32);
                hu0[ki] = __hip_atomic_load(p,     __ATOMIC_RELAXED, __HIP_MEMORY_SCOPE_AGENT);
                hu1[ki] = __hip_atomic_load(p + 1, __ATOMIC_RELAXED, __HIP_MEMORY_SCOPE_AGENT);
            }
            #pragma unroll
            for (int ki = 0; ki < 32; ++ki) {
                union { unsigned long long u[2]; bf16x8 v; } cv;
                cv.u[0] = hu0[ki]; cv.u[1] = hu1[ki];
                bf16x8 br = *(const bf16x8*)&wlds[offh_r + q * 8 + ki * 32];
                bf16x8 bz = *(const bf16x8*)&wlds[offh_z + q * 8 + ki * 32];
                bf16x8 bn = *(const bf16x8*)&wlds[offh_n + q * 8 + ki * 32];
                ar  = __builtin_amdgcn_mfma_f32_16x16x32_bf16(cv.v, br, ar, 0, 0, 0);
                az  = __builtin_amdgcn_mfma_f32_16x16x32_bf16(cv.v, bz, az, 0, 0, 0);
                ahn = __builtin_amdgcn_mfma_f32_16x16x32_bf16(cv.v, bn, ahn, 0, 0, 0);
            }
        }

        // ---- gates + state update (no cross-lane shuffles: r/z/n all at col c) ----
        #pragma unroll
        for (int r = 0; r < 4; ++r) {
            float rr = __builtin_amdgcn_rcpf(1.0f + __expf(-ar[r]));
            float zz = __builtin_amdgcn_rcpf(1.0f + __expf(-az[r]));
            float narg = axn[r] + rr * ahn[r];
            float E = __expf(-2.0f * fabsf(narg));
            float nn = copysignf((1.0f - E) * __builtin_amdgcn_rcpf(1.0f + E), narg);
            float m = mc[r];
            float curr = (1.0f - zz) * nn + zz * hd[r];
            float hnew = m * curr + (1.0f - m) * hd[r];
            out[((size_t)batch_C[r] * S_ + s) * H_ + jd] = hnew;   // plain cached store
            if (t < S_) {
                hd[r] = hnew * (dm[r] * mn[r] + 1.0f - mn[r]);     // pre-drop for step t+1
                mc[r] = mn[r];
                __hip_atomic_store(&hbuf[((t + 1) & 1) * 65536 + batch_C[r] * H_ + jd],
                                   f2bf(hd[r]), __ATOMIC_RELAXED, __HIP_MEMORY_SCOPE_AGENT);
            } else {
                out_last[batch_C[r] * H_ + jd] = hnew;
            }
        }

        if (t < S_) {
            __syncthreads();   // implicit vmcnt(0): agent h-stores acked at mall
            if (tid == 0)      // store-only flag on a private 128B line — no RMW
                __hip_atomic_store(&flags[g * 32], (unsigned)(t + 1),
                                   __ATOMIC_RELAXED, __HIP_MEMORY_SCOPE_AGENT);
        }
    }
}

extern "C" void kernel_launch(void* const* d_in, const int* in_sizes, int n_in,
                              void* d_out, int out_size, void* d_ws, size_t ws_size,
                              hipStream_t stream) {
    (void)in_sizes; (void)n_in; (void)out_size; (void)ws_size;
    const float* x     = (const float*)d_in[0];
    const float* mask  = (const float*)d_in[1];
    const float* inith = (const float*)d_in[2];
    const float* dmask = (const float*)d_in[3];
    const float* Wih   = (const float*)d_in[4];
    const float* Whh   = (const float*)d_in[5];
    const float* bih   = (const float*)d_in[6];
    const float* bhh   = (const float*)d_in[7];
    float* out      = (float*)d_out;
    float* out_last = out + (size_t)B_ * S_ * H_;

    char* ws = (char*)d_ws;
    unsigned* flags       = (unsigned*)ws;                         // 8 KB (64 flags, stride 128B)
    unsigned short* hbuf  = (unsigned short*)(ws + 8192);          // 256 KB (2x h_bf)
    unsigned short* xbf   = (unsigned short*)(ws + 8192 + 262144); // 32 MB

    hipMemsetAsync(ws, 0, 8192, stream);
    gru_prep<<<2048, 256, 0, stream>>>(x, xbf);
    gru_scan<<<NB, 256, 0, stream>>>(xbf, Wih, mask, inith, dmask, Whh, bih, bhh,
                                     out, out_last, flags, hbuf);
}